// Round 1
// baseline (481.082 us; speedup 1.0000x reference)
//
#include <hip/hip_runtime.h>

#define IN_DIM   1024
#define OUT_DIM  1024
#define BATCH    16384

// ---------------------------------------------------------------------------
// Kernel 1: weight normalization + log-jacobian.
// One wave (64 lanes) per row of W. Row o, block r = o>>3:
//   cols [0, r*8)      : tril (identity)
//   cols [r*8, r*8+8)  : diag (exp)
//   cols >= (r+1)*8    : zero
// Wn[o][k] = exp(W_log_scale[o]) * Wm[o][k] / ||Wm[o]||_2
// jac[r][p][c] = log(Wn[o][r*8+c]) = (wls[o] - 0.5*log(ss)) + W[o][r*8+c]
// ---------------------------------------------------------------------------
__global__ __launch_bounds__(256) void prep_kernel(
    const float* __restrict__ W, const float* __restrict__ wls,
    float* __restrict__ Wn, float* __restrict__ jac)
{
    const int warp = threadIdx.x >> 6;
    const int lane = threadIdx.x & 63;
    const int row  = blockIdx.x * 4 + warp;
    const int r    = row >> 3;
    const int d0   = r * 8;        // diag block col start
    const int nk   = d0 + 8;       // nonzero cols [0, nk)
    const float* Wr = W + (size_t)row * IN_DIM;

    float ss = 0.f;
    for (int k = lane; k < nk; k += 64) {
        float v = Wr[k];
        if (k >= d0) v = expf(v);
        ss += v * v;
    }
    #pragma unroll
    for (int off = 32; off >= 1; off >>= 1) ss += __shfl_xor(ss, off);

    const float lscale = wls[row] - 0.5f * logf(ss);
    const float scale  = expf(lscale);

    float* Wnr = Wn + (size_t)row * IN_DIM;
    for (int k = lane; k < IN_DIM; k += 64) {
        float v = 0.f;
        if (k < nk) {
            v = Wr[k];
            if (k >= d0) v = expf(v);
            v *= scale;
        }
        Wnr[k] = v;
    }
    if (lane < 8) {
        jac[r * 64 + (row & 7) * 8 + lane] = lscale + Wr[d0 + lane];
    }
}

// ---------------------------------------------------------------------------
// Kernel 2: y[M][N] = x[M][K] @ Wn[N][K]^T + bias[N]
// fp32 vector GEMM. BM=128 x BN=64 tile, BK=32, 256 threads, 8x4 micro-tile.
// Triangular structure: N-tile at n0 only needs k < n0+BN (multiple of BK).
// ---------------------------------------------------------------------------
#define BM 128
#define BN 64
#define BK 32
#define TM 8
#define TN 4

__global__ __launch_bounds__(256) void gemm_kernel(
    const float* __restrict__ x, const float* __restrict__ Wn,
    const float* __restrict__ bias, float* __restrict__ y)
{
    __shared__ float xs[BK][BM + 4];   // stride 132: 4-way write alias max
    __shared__ float ws[BK][BN + 4];

    const int nt   = (int)gridDim.x - 1 - (int)blockIdx.x;  // heavy tiles first
    const int mt   = blockIdx.y;
    const int n0   = nt * BN;
    const int m0   = mt * BM;
    const int Klim = n0 + BN;          // block-triangular cutoff
    const int t    = threadIdx.x;
    const int tx   = t & 15;           // output col group (4 cols)
    const int ty   = t >> 4;           // output row group (8 rows)

    float acc[TM][TN];
    #pragma unroll
    for (int i = 0; i < TM; ++i)
        #pragma unroll
        for (int j = 0; j < TN; ++j) acc[i][j] = 0.f;

    const int lr = t >> 3;             // staging row 0..31
    const int lk = (t & 7) * 4;        // staging k (float4 col)

    for (int k0 = 0; k0 < Klim; k0 += BK) {
        // stage x tile: BM x BK (transposed into LDS)
        #pragma unroll
        for (int rr = 0; rr < BM; rr += 32) {
            const float4 v = *(const float4*)&x[(size_t)(m0 + lr + rr) * IN_DIM + k0 + lk];
            xs[lk + 0][lr + rr] = v.x;
            xs[lk + 1][lr + rr] = v.y;
            xs[lk + 2][lr + rr] = v.z;
            xs[lk + 3][lr + rr] = v.w;
        }
        // stage Wn tile: BN x BK
        #pragma unroll
        for (int rr = 0; rr < BN; rr += 32) {
            const float4 v = *(const float4*)&Wn[(size_t)(n0 + lr + rr) * IN_DIM + k0 + lk];
            ws[lk + 0][lr + rr] = v.x;
            ws[lk + 1][lr + rr] = v.y;
            ws[lk + 2][lr + rr] = v.z;
            ws[lk + 3][lr + rr] = v.w;
        }
        __syncthreads();

        #pragma unroll
        for (int kk = 0; kk < BK; ++kk) {
            const float4 a0 = *(const float4*)&xs[kk][ty * TM];
            const float4 a1 = *(const float4*)&xs[kk][ty * TM + 4];
            const float4 b  = *(const float4*)&ws[kk][tx * TN];
            const float av[TM] = {a0.x, a0.y, a0.z, a0.w, a1.x, a1.y, a1.z, a1.w};
            const float bv[TN] = {b.x, b.y, b.z, b.w};
            #pragma unroll
            for (int i = 0; i < TM; ++i)
                #pragma unroll
                for (int j = 0; j < TN; ++j)
                    acc[i][j] = fmaf(av[i], bv[j], acc[i][j]);
        }
        __syncthreads();
    }

    const float4 bb = *(const float4*)&bias[n0 + tx * TN];
    #pragma unroll
    for (int i = 0; i < TM; ++i) {
        const int row = m0 + ty * TM + i;
        float4 o;
        o.x = acc[i][0] + bb.x;
        o.y = acc[i][1] + bb.y;
        o.z = acc[i][2] + bb.z;
        o.w = acc[i][3] + bb.w;
        *(float4*)&y[(size_t)row * OUT_DIM + n0 + tx * TN] = o;
    }
}

// ---------------------------------------------------------------------------
extern "C" void kernel_launch(void* const* d_in, const int* in_sizes, int n_in,
                              void* d_out, int out_size, void* d_ws, size_t ws_size,
                              hipStream_t stream)
{
    const float* x    = (const float*)d_in[0];
    const float* W    = (const float*)d_in[1];
    const float* bias = (const float*)d_in[2];
    const float* wls  = (const float*)d_in[3];
    // d_in[4], d_in[5]: structural masks (deterministic; encoded in index math)

    float* Wn  = (float*)d_ws;                       // 1024*1024*4 = 4 MiB scratch
    float* y   = (float*)d_out;                      // [16384][1024]
    float* jac = y + (size_t)BATCH * OUT_DIM;        // [128][8][8]

    prep_kernel<<<OUT_DIM / 4, 256, 0, stream>>>(W, wls, Wn, jac);

    dim3 grid(OUT_DIM / BN, BATCH / BM);             // (16, 128), heavy-first in x
    gemm_kernel<<<grid, 256, 0, stream>>>(x, Wn, bias, y);
}

// Round 2
// 336.147 us; speedup vs baseline: 1.4312x; 1.4312x over previous
//
#include <hip/hip_runtime.h>

#define IN_DIM   1024
#define OUT_DIM  1024
#define BATCH    16384

typedef __attribute__((ext_vector_type(8))) short          bf16x8;
typedef __attribute__((ext_vector_type(8))) unsigned short u16x8;
typedef __attribute__((ext_vector_type(4))) float          f32x4;

__device__ __forceinline__ unsigned short f2bf(float f) {
    unsigned u = __float_as_uint(f);
    u += 0x7FFFu + ((u >> 16) & 1u);          // round-to-nearest-even
    return (unsigned short)(u >> 16);
}
__device__ __forceinline__ float bf2f(unsigned short h) {
    return __uint_as_float((unsigned)h << 16);
}

// ---------------------------------------------------------------------------
// Kernel 1: weight normalization -> split bf16 (wh + wl), plus log-jacobian.
// One wave per row. Row o, block r=o>>3: cols [0,r*8) tril, [r*8,r*8+8) diag
// (exp), rest zero.  Wn = exp(wls)*Wm/||Wm||;  jac = wls - 0.5*log(ss) + W_diag
// ---------------------------------------------------------------------------
__global__ __launch_bounds__(256) void prep_kernel(
    const float* __restrict__ W, const float* __restrict__ wls,
    unsigned short* __restrict__ wh, unsigned short* __restrict__ wl,
    float* __restrict__ jac)
{
    const int warp = threadIdx.x >> 6;
    const int lane = threadIdx.x & 63;
    const int row  = blockIdx.x * 4 + warp;
    const int r    = row >> 3;
    const int d0   = r * 8;
    const int nk   = d0 + 8;
    const float* Wr = W + (size_t)row * IN_DIM;

    float ss = 0.f;
    for (int k = lane; k < nk; k += 64) {
        float v = Wr[k];
        if (k >= d0) v = expf(v);
        ss += v * v;
    }
    #pragma unroll
    for (int off = 32; off >= 1; off >>= 1) ss += __shfl_xor(ss, off);

    const float lscale = wls[row] - 0.5f * logf(ss);
    const float scale  = expf(lscale);

    for (int k = lane; k < IN_DIM; k += 64) {
        float v = 0.f;
        if (k < nk) {
            v = Wr[k];
            if (k >= d0) v = expf(v);
            v *= scale;
        }
        const unsigned short h = f2bf(v);
        wh[(size_t)row * IN_DIM + k] = h;
        wl[(size_t)row * IN_DIM + k] = f2bf(v - bf2f(h));
    }
    if (lane < 8) jac[r * 64 + (row & 7) * 8 + lane] = lscale + Wr[d0 + lane];
}

// ---------------------------------------------------------------------------
// Kernel 2: y = x @ Wn^T + bias via bf16x2-split MFMA (hi*hi + hi*lo + lo*hi).
// 128x128 tile, BK=32, 4 waves (2x2, 64x64 each), 4x4 frags of 16x16x32.
// x converted fp32->(hi,lo) during staging (fused, no extra HBM pass).
// Triangular: N-tile nt only needs k < n0+128.
// ---------------------------------------------------------------------------
#define BM   128
#define BN   128
#define BK   32
#define LDST 40      // padded LDS row stride (bf16 elems) = 80 B -> conflict-free frag reads

__global__ __launch_bounds__(256, 3) void gemm_kernel(
    const float* __restrict__ x,
    const unsigned short* __restrict__ wh, const unsigned short* __restrict__ wl,
    const float* __restrict__ bias, float* __restrict__ y)
{
    __shared__ unsigned short xh_s[BM * LDST];
    __shared__ unsigned short xl_s[BM * LDST];
    __shared__ unsigned short wh_s[BN * LDST];
    __shared__ unsigned short wl_s[BN * LDST];

    const int nt   = (int)gridDim.x - 1 - (int)blockIdx.x;   // heavy tiles first
    const int n0   = nt * BN;
    const int m0   = (int)blockIdx.y * BM;
    const int Klim = n0 + BN;                                // block-triangular cutoff

    const int t    = threadIdx.x;
    const int lane = t & 63;
    const int wid  = t >> 6;
    const int wr   = wid >> 1;          // wave row 0..1
    const int wc   = wid & 1;           // wave col 0..1

    // staging coords: x -> 16 floats/thread, w -> 2x 8-bf16 chunks per array
    const int sxr = t >> 1;             // x row 0..127
    const int sxc = (t & 1) * 16;       // x col chunk
    const int swr = t >> 2;             // w row 0..63 (and +64)
    const int swc = (t & 3) * 8;        // w col chunk

    const float*          xg  = x  + (size_t)(m0 + sxr) * IN_DIM + sxc;
    const unsigned short* whg = wh + (size_t)(n0 + swr) * IN_DIM + swc;
    const unsigned short* wlg = wl + (size_t)(n0 + swr) * IN_DIM + swc;

    // MFMA fragment LDS offsets (A: row=lane&15, k=(lane>>4)*8+j; B same form)
    const int fl    = lane & 15;
    const int fk    = (lane >> 4) * 8;
    const int a_off = (wr * 64 + fl) * LDST + fk;
    const int b_off = (wc * 64 + fl) * LDST + fk;

    f32x4 acc[4][4];
    #pragma unroll
    for (int i = 0; i < 4; ++i)
        #pragma unroll
        for (int j = 0; j < 4; ++j) acc[i][j] = (f32x4){0.f, 0.f, 0.f, 0.f};

    float4 xv[4];
    int4   wv[4];

    auto LOAD = [&](int k0) {
        const float* xp = xg + k0;
        xv[0] = *(const float4*)(xp + 0);
        xv[1] = *(const float4*)(xp + 4);
        xv[2] = *(const float4*)(xp + 8);
        xv[3] = *(const float4*)(xp + 12);
        wv[0] = *(const int4*)(whg + k0);
        wv[1] = *(const int4*)(whg + (size_t)64 * IN_DIM + k0);
        wv[2] = *(const int4*)(wlg + k0);
        wv[3] = *(const int4*)(wlg + (size_t)64 * IN_DIM + k0);
    };
    auto STORE = [&]() {
        const float f[16] = {xv[0].x, xv[0].y, xv[0].z, xv[0].w,
                             xv[1].x, xv[1].y, xv[1].z, xv[1].w,
                             xv[2].x, xv[2].y, xv[2].z, xv[2].w,
                             xv[3].x, xv[3].y, xv[3].z, xv[3].w};
        u16x8 h0, h1, l0, l1;
        #pragma unroll
        for (int i = 0; i < 8; ++i) {
            const unsigned short h = f2bf(f[i]);
            h0[i] = (unsigned short)h;  l0[i] = f2bf(f[i] - bf2f(h));
            const unsigned short g = f2bf(f[i + 8]);
            h1[i] = (unsigned short)g;  l1[i] = f2bf(f[i + 8] - bf2f(g));
        }
        *(u16x8*)&xh_s[sxr * LDST + sxc]       = h0;
        *(u16x8*)&xh_s[sxr * LDST + sxc + 8]   = h1;
        *(u16x8*)&xl_s[sxr * LDST + sxc]       = l0;
        *(u16x8*)&xl_s[sxr * LDST + sxc + 8]   = l1;
        *(int4*)&wh_s[swr * LDST + swc]        = wv[0];
        *(int4*)&wh_s[(swr + 64) * LDST + swc] = wv[1];
        *(int4*)&wl_s[swr * LDST + swc]        = wv[2];
        *(int4*)&wl_s[(swr + 64) * LDST + swc] = wv[3];
    };

    LOAD(0);
    STORE();
    __syncthreads();

    for (int k0 = 0; k0 < Klim; k0 += BK) {
        const bool more = (k0 + BK) < Klim;
        if (more) LOAD(k0 + BK);          // issue next-tile loads before compute

        bf16x8 bh[4], bl[4];
        #pragma unroll
        for (int fc = 0; fc < 4; ++fc) {
            bh[fc] = *(const bf16x8*)&wh_s[b_off + fc * 16 * LDST];
            bl[fc] = *(const bf16x8*)&wl_s[b_off + fc * 16 * LDST];
        }
        #pragma unroll
        for (int fr = 0; fr < 4; ++fr) {
            const bf16x8 ah = *(const bf16x8*)&xh_s[a_off + fr * 16 * LDST];
            const bf16x8 al = *(const bf16x8*)&xl_s[a_off + fr * 16 * LDST];
            #pragma unroll
            for (int fc = 0; fc < 4; ++fc) {
                acc[fr][fc] = __builtin_amdgcn_mfma_f32_16x16x32_bf16(ah, bh[fc], acc[fr][fc], 0, 0, 0);
                acc[fr][fc] = __builtin_amdgcn_mfma_f32_16x16x32_bf16(ah, bl[fc], acc[fr][fc], 0, 0, 0);
                acc[fr][fc] = __builtin_amdgcn_mfma_f32_16x16x32_bf16(al, bh[fc], acc[fr][fc], 0, 0, 0);
            }
        }
        __syncthreads();
        if (more) STORE();
        __syncthreads();
    }

    // epilogue: bias + store (D: row=(lane>>4)*4+reg, col=lane&15)
    float bv[4];
    #pragma unroll
    for (int fc = 0; fc < 4; ++fc) bv[fc] = bias[n0 + wc * 64 + fc * 16 + fl];

    #pragma unroll
    for (int fr = 0; fr < 4; ++fr) {
        const int row0 = m0 + wr * 64 + fr * 16 + (lane >> 4) * 4;
        #pragma unroll
        for (int fc = 0; fc < 4; ++fc) {
            const int col = n0 + wc * 64 + fc * 16 + fl;
            #pragma unroll
            for (int i = 0; i < 4; ++i)
                y[(size_t)(row0 + i) * OUT_DIM + col] = acc[fr][fc][i] + bv[fc];
        }
    }
}

// ---------------------------------------------------------------------------
extern "C" void kernel_launch(void* const* d_in, const int* in_sizes, int n_in,
                              void* d_out, int out_size, void* d_ws, size_t ws_size,
                              hipStream_t stream)
{
    const float* x    = (const float*)d_in[0];
    const float* W    = (const float*)d_in[1];
    const float* bias = (const float*)d_in[2];
    const float* wls  = (const float*)d_in[3];
    // d_in[4], d_in[5]: structural int masks (encoded in index math)

    unsigned short* wh = (unsigned short*)d_ws;                 // 2 MiB
    unsigned short* wl = wh + (size_t)OUT_DIM * IN_DIM;         // 2 MiB
    float* y   = (float*)d_out;                                 // [16384][1024]
    float* jac = y + (size_t)BATCH * OUT_DIM;                   // [128][8][8]

    prep_kernel<<<OUT_DIM / 4, 256, 0, stream>>>(W, wls, wh, wl, jac);

    dim3 grid(OUT_DIM / BN, BATCH / BM);                        // (8, 128)
    gemm_kernel<<<grid, 256, 0, stream>>>(x, wh, wl, bias, y);
}

// Round 3
// 297.895 us; speedup vs baseline: 1.6149x; 1.1284x over previous
//
#include <hip/hip_runtime.h>

#define IN_DIM   1024
#define OUT_DIM  1024
#define BATCH    16384

typedef __attribute__((ext_vector_type(8))) short          bf16x8;
typedef __attribute__((ext_vector_type(8))) unsigned short u16x8;
typedef __attribute__((ext_vector_type(4))) unsigned short u16x4;
typedef __attribute__((ext_vector_type(4))) float          f32x4;

__device__ __forceinline__ unsigned short f2bf(float f) {
    unsigned u = __float_as_uint(f);
    u += 0x7FFFu + ((u >> 16) & 1u);          // round-to-nearest-even
    return (unsigned short)(u >> 16);
}
__device__ __forceinline__ float bf2f(unsigned short h) {
    return __uint_as_float((unsigned)h << 16);
}

// ---------------------------------------------------------------------------
// Kernel 1: weight normalization -> split bf16 (wh + wl), plus log-jacobian.
// One wave per row. Row o, block r=o>>3: cols [0,r*8) tril, [r*8,r*8+8) diag
// (exp), rest zero. Diag block is 8-aligned so every 4-aligned float4 is
// entirely tril or entirely diag.
// ---------------------------------------------------------------------------
__global__ __launch_bounds__(256) void prep_kernel(
    const float* __restrict__ W, const float* __restrict__ wls,
    unsigned short* __restrict__ wh, unsigned short* __restrict__ wl,
    float* __restrict__ jac)
{
    const int warp = threadIdx.x >> 6;
    const int lane = threadIdx.x & 63;
    const int row  = blockIdx.x * 4 + warp;
    const int r    = row >> 3;
    const int d0   = r * 8;
    const int nk   = d0 + 8;
    const float* Wr = W + (size_t)row * IN_DIM;

    float ss = 0.f;
    for (int k = lane * 4; k < nk; k += 256) {
        float4 v = *(const float4*)&Wr[k];
        if (k >= d0) { v.x = expf(v.x); v.y = expf(v.y); v.z = expf(v.z); v.w = expf(v.w); }
        ss += v.x * v.x + v.y * v.y + v.z * v.z + v.w * v.w;
    }
    #pragma unroll
    for (int off = 32; off >= 1; off >>= 1) ss += __shfl_xor(ss, off);

    const float lscale = wls[row] - 0.5f * logf(ss);
    const float scale  = expf(lscale);

    for (int k = lane * 4; k < IN_DIM; k += 256) {
        float4 v = {0.f, 0.f, 0.f, 0.f};
        if (k < nk) {
            v = *(const float4*)&Wr[k];
            if (k >= d0) { v.x = expf(v.x); v.y = expf(v.y); v.z = expf(v.z); v.w = expf(v.w); }
            v.x *= scale; v.y *= scale; v.z *= scale; v.w *= scale;
        }
        u16x4 h, l;
        const float f[4] = {v.x, v.y, v.z, v.w};
        #pragma unroll
        for (int i = 0; i < 4; ++i) {
            h[i] = f2bf(f[i]);
            l[i] = f2bf(f[i] - bf2f(h[i]));
        }
        *(u16x4*)&wh[(size_t)row * IN_DIM + k] = h;
        *(u16x4*)&wl[(size_t)row * IN_DIM + k] = l;
    }
    if (lane < 8) jac[r * 64 + (row & 7) * 8 + lane] = lscale + Wr[d0 + lane];
}

// ---------------------------------------------------------------------------
// Kernel 2: y = x @ Wn^T + bias via bf16x2-split MFMA (hh + hl + lh).
// 128x128 tile, BK=32, 4 waves (2x2), double-buffered LDS (80 KB, 1 barrier
// per K-step), XCD-affine block swizzle, LDS-transposed coalesced epilogue.
// ---------------------------------------------------------------------------
#define BM   128
#define BN   128
#define BK   32
#define LDST 40      // padded LDS row stride (bf16) = 80 B
#define YLD  132     // epilogue fp32 row stride

__global__ __launch_bounds__(256, 2) void gemm_kernel(
    const float* __restrict__ x,
    const unsigned short* __restrict__ wh, const unsigned short* __restrict__ wl,
    const float* __restrict__ bias, float* __restrict__ y)
{
    __shared__ __align__(16) unsigned short smem[2 * 4 * BM * LDST];  // 80 KB

    // XCD-affine swizzle: xcd = bid&7 owns 16 consecutive M-tiles; the 8
    // N-tiles sharing one x-panel are consecutive blocks -> L2 reuse.
    // Heavy N-tiles (Klim=1024) dispatch first.
    const int bid = (int)blockIdx.x;
    const int xcd = bid & 7;
    const int idx = bid >> 3;
    const int mt  = xcd * 16 + (idx >> 3);
    const int nt  = 7 - (idx & 7);
    const int m0  = mt * BM;
    const int n0  = nt * BN;
    const int Klim = n0 + BN;          // block-triangular cutoff

    const int t    = threadIdx.x;
    const int lane = t & 63;
    const int wid  = t >> 6;
    const int wr   = wid >> 1;
    const int wc   = wid & 1;

    // staging coords
    const int sxr = t >> 1;            // x row 0..127
    const int sxc = (t & 1) * 16;      // x col chunk (16 floats)
    const int swr = t >> 2;            // w row 0..63 (and +64)
    const int swc = (t & 3) * 8;       // w col chunk (8 bf16)

    const float*          xg  = x  + (size_t)(m0 + sxr) * IN_DIM + sxc;
    const unsigned short* whg = wh + (size_t)(n0 + swr) * IN_DIM + swc;
    const unsigned short* wlg = wl + (size_t)(n0 + swr) * IN_DIM + swc;

    // MFMA fragment offsets (A/B: row=lane&15, k=(lane>>4)*8+j)
    const int fl    = lane & 15;
    const int fk    = (lane >> 4) * 8;
    const int a_off = (wr * 64 + fl) * LDST + fk;
    const int b_off = (wc * 64 + fl) * LDST + fk;

    f32x4 acc[4][4];
    #pragma unroll
    for (int i = 0; i < 4; ++i)
        #pragma unroll
        for (int j = 0; j < 4; ++j) acc[i][j] = (f32x4){0.f, 0.f, 0.f, 0.f};

    float4 xv[4];
    int4   wv[4];

    auto LOAD = [&](int k0) {
        const float* xp = xg + k0;
        xv[0] = *(const float4*)(xp + 0);
        xv[1] = *(const float4*)(xp + 4);
        xv[2] = *(const float4*)(xp + 8);
        xv[3] = *(const float4*)(xp + 12);
        wv[0] = *(const int4*)(whg + k0);
        wv[1] = *(const int4*)(whg + (size_t)64 * IN_DIM + k0);
        wv[2] = *(const int4*)(wlg + k0);
        wv[3] = *(const int4*)(wlg + (size_t)64 * IN_DIM + k0);
    };
    auto STOREb = [&](int b) {
        unsigned short* xhp = smem + ((b << 2) + 0) * (BM * LDST);
        unsigned short* xlp = smem + ((b << 2) + 1) * (BM * LDST);
        unsigned short* whp = smem + ((b << 2) + 2) * (BM * LDST);
        unsigned short* wlp = smem + ((b << 2) + 3) * (BM * LDST);
        const float f[16] = {xv[0].x, xv[0].y, xv[0].z, xv[0].w,
                             xv[1].x, xv[1].y, xv[1].z, xv[1].w,
                             xv[2].x, xv[2].y, xv[2].z, xv[2].w,
                             xv[3].x, xv[3].y, xv[3].z, xv[3].w};
        u16x8 h0, h1, l0, l1;
        #pragma unroll
        for (int i = 0; i < 8; ++i) {
            const unsigned short h = f2bf(f[i]);
            h0[i] = h;  l0[i] = f2bf(f[i] - bf2f(h));
            const unsigned short g = f2bf(f[i + 8]);
            h1[i] = g;  l1[i] = f2bf(f[i + 8] - bf2f(g));
        }
        *(u16x8*)&xhp[sxr * LDST + sxc]       = h0;
        *(u16x8*)&xhp[sxr * LDST + sxc + 8]   = h1;
        *(u16x8*)&xlp[sxr * LDST + sxc]       = l0;
        *(u16x8*)&xlp[sxr * LDST + sxc + 8]   = l1;
        *(int4*)&whp[swr * LDST + swc]        = wv[0];
        *(int4*)&whp[(swr + 64) * LDST + swc] = wv[1];
        *(int4*)&wlp[swr * LDST + swc]        = wv[2];
        *(int4*)&wlp[(swr + 64) * LDST + swc] = wv[3];
    };
    auto COMPUTE = [&](int b) {
        const unsigned short* xhp = smem + ((b << 2) + 0) * (BM * LDST);
        const unsigned short* xlp = smem + ((b << 2) + 1) * (BM * LDST);
        const unsigned short* whp = smem + ((b << 2) + 2) * (BM * LDST);
        const unsigned short* wlp = smem + ((b << 2) + 3) * (BM * LDST);
        bf16x8 bh[4], bl[4];
        #pragma unroll
        for (int fc = 0; fc < 4; ++fc) {
            bh[fc] = *(const bf16x8*)&whp[b_off + fc * 16 * LDST];
            bl[fc] = *(const bf16x8*)&wlp[b_off + fc * 16 * LDST];
        }
        #pragma unroll
        for (int fr = 0; fr < 4; ++fr) {
            const bf16x8 ah = *(const bf16x8*)&xhp[a_off + fr * 16 * LDST];
            const bf16x8 al = *(const bf16x8*)&xlp[a_off + fr * 16 * LDST];
            #pragma unroll
            for (int fc = 0; fc < 4; ++fc) {
                acc[fr][fc] = __builtin_amdgcn_mfma_f32_16x16x32_bf16(ah, bh[fc], acc[fr][fc], 0, 0, 0);
                acc[fr][fc] = __builtin_amdgcn_mfma_f32_16x16x32_bf16(ah, bl[fc], acc[fr][fc], 0, 0, 0);
                acc[fr][fc] = __builtin_amdgcn_mfma_f32_16x16x32_bf16(al, bh[fc], acc[fr][fc], 0, 0, 0);
            }
        }
    };

    LOAD(0);
    STOREb(0);
    __syncthreads();

    int cur = 0;
    for (int k0 = 0; k0 < Klim; k0 += BK) {
        const bool more = (k0 + BK) < Klim;
        if (more) LOAD(k0 + BK);       // issue next-tile global loads
        COMPUTE(cur);                  // ds_read + MFMA on current buffer
        if (more) STOREb(cur ^ 1);     // vmcnt drain + LDS write (other buffer)
        __syncthreads();               // ONE barrier per K-step
        cur ^= 1;
    }

    // ---- epilogue: LDS-transpose -> fully coalesced float4 row writes ----
    float* yt = (float*)smem;          // [128][YLD] fp32, 67.6 KB
    #pragma unroll
    for (int fr = 0; fr < 4; ++fr) {
        const int row0 = wr * 64 + fr * 16 + (lane >> 4) * 4;
        #pragma unroll
        for (int fc = 0; fc < 4; ++fc) {
            const int col = wc * 64 + fc * 16 + fl;
            #pragma unroll
            for (int i = 0; i < 4; ++i)
                yt[(row0 + i) * YLD + col] = acc[fr][fc][i];
        }
    }
    __syncthreads();

    float4 bb = *(const float4*)&bias[n0 + (t & 31) * 4];
    #pragma unroll
    for (int p = 0; p < 16; ++p) {
        const int row = p * 8 + (t >> 5);
        float4 v = *(const float4*)&yt[row * YLD + (t & 31) * 4];
        v.x += bb.x; v.y += bb.y; v.z += bb.z; v.w += bb.w;
        *(float4*)&y[(size_t)(m0 + row) * OUT_DIM + n0 + (t & 31) * 4] = v;
    }
}

// ---------------------------------------------------------------------------
extern "C" void kernel_launch(void* const* d_in, const int* in_sizes, int n_in,
                              void* d_out, int out_size, void* d_ws, size_t ws_size,
                              hipStream_t stream)
{
    const float* x    = (const float*)d_in[0];
    const float* W    = (const float*)d_in[1];
    const float* bias = (const float*)d_in[2];
    const float* wls  = (const float*)d_in[3];
    // d_in[4], d_in[5]: structural int masks (encoded in index math)

    unsigned short* wh = (unsigned short*)d_ws;                 // 2 MiB
    unsigned short* wl = wh + (size_t)OUT_DIM * IN_DIM;         // 2 MiB
    float* y   = (float*)d_out;                                 // [16384][1024]
    float* jac = y + (size_t)BATCH * OUT_DIM;                   // [128][8][8]

    prep_kernel<<<OUT_DIM / 4, 256, 0, stream>>>(W, wls, wh, wl, jac);

    gemm_kernel<<<(OUT_DIM / BN) * (BATCH / BM), 256, 0, stream>>>(x, wh, wl, bias, y);
}

// Round 4
// 180.820 us; speedup vs baseline: 2.6606x; 1.6475x over previous
//
#include <hip/hip_runtime.h>

#define IN_DIM   1024
#define OUT_DIM  1024
#define BATCH    16384

#define BM 128
#define BN 256
#define BK 32
#define RS 32          // LDS row stride in bf16 elems (64 B dense rows)
#define BUFE 24576     // ushort elems per LDS buffer (48 KB)

typedef __attribute__((ext_vector_type(8))) short          bf16x8;
typedef __attribute__((ext_vector_type(8))) unsigned short u16x8;
typedef __attribute__((ext_vector_type(4))) unsigned short u16x4;
typedef __attribute__((ext_vector_type(4))) float          f32x4;

__device__ __forceinline__ unsigned short f2bf(float f) {
    unsigned u = __float_as_uint(f);
    u += 0x7FFFu + ((u >> 16) & 1u);          // round-to-nearest-even
    return (unsigned short)(u >> 16);
}
__device__ __forceinline__ float bf2f(unsigned short h) {
    return __uint_as_float((unsigned)h << 16);
}

#define GLOAD_LDS16(g, l)                                                      \
    __builtin_amdgcn_global_load_lds(                                          \
        (const __attribute__((address_space(1))) unsigned int*)(g),            \
        (__attribute__((address_space(3))) unsigned int*)(l), 16, 0, 0)

// ---------------------------------------------------------------------------
// Kernel 1: weight normalization -> split bf16 planes (wh + wl) + log-jac.
// One wave per row. Row o, block r=o>>3: cols [0,r*8) tril, [r*8,r*8+8) diag
// (exp), rest zero.
// ---------------------------------------------------------------------------
__global__ __launch_bounds__(256) void prep_kernel(
    const float* __restrict__ W, const float* __restrict__ wls,
    unsigned short* __restrict__ wh, unsigned short* __restrict__ wl,
    float* __restrict__ jac)
{
    const int warp = threadIdx.x >> 6;
    const int lane = threadIdx.x & 63;
    const int row  = blockIdx.x * 4 + warp;
    const int r    = row >> 3;
    const int d0   = r * 8;
    const int nk   = d0 + 8;
    const float* Wr = W + (size_t)row * IN_DIM;

    float ss = 0.f;
    for (int k = lane * 4; k < nk; k += 256) {
        float4 v = *(const float4*)&Wr[k];
        if (k >= d0) { v.x = expf(v.x); v.y = expf(v.y); v.z = expf(v.z); v.w = expf(v.w); }
        ss += v.x * v.x + v.y * v.y + v.z * v.z + v.w * v.w;
    }
    #pragma unroll
    for (int off = 32; off >= 1; off >>= 1) ss += __shfl_xor(ss, off);

    const float lscale = wls[row] - 0.5f * logf(ss);
    const float scale  = expf(lscale);

    for (int k = lane * 4; k < IN_DIM; k += 256) {
        float4 v = {0.f, 0.f, 0.f, 0.f};
        if (k < nk) {
            v = *(const float4*)&Wr[k];
            if (k >= d0) { v.x = expf(v.x); v.y = expf(v.y); v.z = expf(v.z); v.w = expf(v.w); }
            v.x *= scale; v.y *= scale; v.z *= scale; v.w *= scale;
        }
        u16x4 h, l;
        const float f[4] = {v.x, v.y, v.z, v.w};
        #pragma unroll
        for (int i = 0; i < 4; ++i) {
            h[i] = f2bf(f[i]);
            l[i] = f2bf(f[i] - bf2f(h[i]));
        }
        *(u16x4*)&wh[(size_t)row * IN_DIM + k] = h;
        *(u16x4*)&wl[(size_t)row * IN_DIM + k] = l;
    }
    if (lane < 8) jac[r * 64 + (row & 7) * 8 + lane] = lscale + Wr[d0 + lane];
}

// ---------------------------------------------------------------------------
// Kernel 2: y = x @ Wn^T + bias, bf16x2-split MFMA (hh + hl + lh).
// 128x256 tile, BK=32, 512 thr / 8 waves (2x4 -> 64x64 per wave).
// W planes staged via global_load_lds (linear 64B rows); x reg-staged with
// fused fp32->bf16hi/lo conversion. Double-buffered, 1 barrier per K-step.
// Heavy-first segments (nt=3..0) for load balance + XCD-affine mt swizzle.
// ---------------------------------------------------------------------------
__global__ __launch_bounds__(512, 2) void gemm_kernel(
    const float* __restrict__ x,
    const unsigned short* __restrict__ wh, const unsigned short* __restrict__ wl,
    const float* __restrict__ bias, float* __restrict__ y)
{
    __shared__ __align__(16) unsigned short smem[2 * BUFE];  // 96 KB
    // buffer b at smem + b*BUFE: xh[BM*RS] | xl[BM*RS] | wh[BN*RS] | wl[BN*RS]

    const int bid = (int)blockIdx.x;
    const int seg = bid >> 7;                 // 0..3, dispatched first = heaviest
    const int sb  = bid & 127;
    const int nt  = 3 - seg;
    const int mt  = (sb & 7) * 16 + (sb >> 3);  // XCD-affine: xcd owns 16 mts
    const int m0  = mt * BM;
    const int n0  = nt * BN;
    const int Klim = n0 + BN;                 // block-triangular cutoff

    const int t    = threadIdx.x;
    const int lane = t & 63;
    const int wid  = t >> 6;
    const int wr   = wid >> 2;                // 0..1
    const int wc   = wid & 3;                 // 0..3

    // x staging: thread t -> row t>>2 (0..127), 8 floats at col (t&3)*8
    const int sxr = t >> 2;
    const int sxc = (t & 3) * 8;
    const float* xg = x + (size_t)(m0 + sxr) * IN_DIM + sxc;

    // W staging: wave wid stages rows [wid*32, wid*32+32) per plane,
    // as two 1KB global_load_lds chunks (16 rows x 64B each).
    const unsigned short* whg = wh + (size_t)(n0 + wid * 32 + (lane >> 2)) * IN_DIM + (lane & 3) * 8;
    const unsigned short* wlg = wl + (size_t)(n0 + wid * 32 + (lane >> 2)) * IN_DIM + (lane & 3) * 8;

    // MFMA fragment offsets (A/B: row=lane&15, k=(lane>>4)*8)
    const int fl = lane & 15;
    const int fk = (lane >> 4) * 8;
    const int a_base = (wr * 64 + fl) * RS + fk;
    const int b_base = (wc * 64 + fl) * RS + fk;

    f32x4 acc[4][4];
    #pragma unroll
    for (int i = 0; i < 4; ++i)
        #pragma unroll
        for (int j = 0; j < 4; ++j) acc[i][j] = (f32x4){0.f, 0.f, 0.f, 0.f};

    float4 xva, xvb;

    auto LOAD_X = [&](int k0) {
        xva = *(const float4*)(xg + k0);
        xvb = *(const float4*)(xg + k0 + 4);
    };
    auto STAGE_W = [&](int b, int k0) {
        unsigned short* whp = smem + b * BUFE + 2 * BM * RS;
        unsigned short* wlp = whp + BN * RS;
        const unsigned short* gh = whg + k0;
        const unsigned short* gl = wlg + k0;
        GLOAD_LDS16(gh,                whp + wid * 1024);        // rows wid*32..+15
        GLOAD_LDS16(gh + 16 * IN_DIM,  whp + wid * 1024 + 512);  // rows +16..+31
        GLOAD_LDS16(gl,                wlp + wid * 1024);
        GLOAD_LDS16(gl + 16 * IN_DIM,  wlp + wid * 1024 + 512);
    };
    auto CVT_X = [&](int b) {
        unsigned short* xhp = smem + b * BUFE;
        unsigned short* xlp = xhp + BM * RS;
        const float f[8] = {xva.x, xva.y, xva.z, xva.w, xvb.x, xvb.y, xvb.z, xvb.w};
        u16x8 h, l;
        #pragma unroll
        for (int i = 0; i < 8; ++i) {
            h[i] = f2bf(f[i]);
            l[i] = f2bf(f[i] - bf2f(h[i]));
        }
        *(u16x8*)&xhp[sxr * RS + sxc] = h;
        *(u16x8*)&xlp[sxr * RS + sxc] = l;
    };
    auto COMPUTE = [&](int b) {
        const unsigned short* xhp = smem + b * BUFE;
        const unsigned short* xlp = xhp + BM * RS;
        const unsigned short* whp = xlp + BM * RS;
        const unsigned short* wlp = whp + BN * RS;
        bf16x8 bh[4], bl[4];
        #pragma unroll
        for (int fc = 0; fc < 4; ++fc) {
            bh[fc] = *(const bf16x8*)&whp[b_base + fc * 16 * RS];
            bl[fc] = *(const bf16x8*)&wlp[b_base + fc * 16 * RS];
        }
        #pragma unroll
        for (int fr = 0; fr < 4; ++fr) {
            const bf16x8 ah = *(const bf16x8*)&xhp[a_base + fr * 16 * RS];
            const bf16x8 al = *(const bf16x8*)&xlp[a_base + fr * 16 * RS];
            #pragma unroll
            for (int fc = 0; fc < 4; ++fc) {
                acc[fr][fc] = __builtin_amdgcn_mfma_f32_16x16x32_bf16(ah, bh[fc], acc[fr][fc], 0, 0, 0);
                acc[fr][fc] = __builtin_amdgcn_mfma_f32_16x16x32_bf16(ah, bl[fc], acc[fr][fc], 0, 0, 0);
                acc[fr][fc] = __builtin_amdgcn_mfma_f32_16x16x32_bf16(al, bh[fc], acc[fr][fc], 0, 0, 0);
            }
        }
    };

    // prologue
    LOAD_X(0);
    STAGE_W(0, 0);
    CVT_X(0);
    __syncthreads();                 // drains vmcnt(0)+lgkm: buf0 fully staged

    int cur = 0;
    for (int k0 = 0; k0 < Klim; k0 += BK) {
        const bool more = (k0 + BK) < Klim;
        if (more) {
            LOAD_X(k0 + BK);         // x(i+1) -> regs (consumed after compute)
            STAGE_W(cur ^ 1, k0 + BK); // W(i+1) -> LDS, drains at next barrier
        }
        COMPUTE(cur);
        if (more) CVT_X(cur ^ 1);    // compiler waits exactly the x loads
        __syncthreads();
        cur ^= 1;
    }

    // ---- epilogue: LDS transpose -> coalesced float4 stores, 2 col-halves ----
    float* yt = (float*)smem;        // [128][132] fp32 = 67.6 KB
    const int erow = t >> 2;
    const int ec0  = (t & 3) * 4;
    #pragma unroll
    for (int h = 0; h < 2; ++h) {
        if ((wc >> 1) == h) {
            #pragma unroll
            for (int fr = 0; fr < 4; ++fr) {
                const int row0 = wr * 64 + fr * 16 + (lane >> 4) * 4;
                #pragma unroll
                for (int fc = 0; fc < 4; ++fc) {
                    const int col = (wc & 1) * 64 + fc * 16 + fl;
                    #pragma unroll
                    for (int i = 0; i < 4; ++i)
                        yt[(row0 + i) * 132 + col] = acc[fr][fc][i];
                }
            }
        }
        __syncthreads();
        #pragma unroll
        for (int j = 0; j < 8; ++j) {
            const int col = ec0 + j * 16;
            float4 v = *(const float4*)&yt[erow * 132 + col];
            const float4 bb = *(const float4*)&bias[n0 + h * 128 + col];
            v.x += bb.x; v.y += bb.y; v.z += bb.z; v.w += bb.w;
            *(float4*)&y[(size_t)(m0 + erow) * OUT_DIM + n0 + h * 128 + col] = v;
        }
        __syncthreads();
    }
}

// ---------------------------------------------------------------------------
extern "C" void kernel_launch(void* const* d_in, const int* in_sizes, int n_in,
                              void* d_out, int out_size, void* d_ws, size_t ws_size,
                              hipStream_t stream)
{
    const float* x    = (const float*)d_in[0];
    const float* W    = (const float*)d_in[1];
    const float* bias = (const float*)d_in[2];
    const float* wls  = (const float*)d_in[3];
    // d_in[4], d_in[5]: structural int masks (encoded in index math)

    unsigned short* wh = (unsigned short*)d_ws;                 // 2 MiB
    unsigned short* wl = wh + (size_t)OUT_DIM * IN_DIM;         // 2 MiB
    float* y   = (float*)d_out;                                 // [16384][1024]
    float* jac = y + (size_t)BATCH * OUT_DIM;                   // [128][8][8]

    prep_kernel<<<OUT_DIM / 4, 256, 0, stream>>>(W, wls, wh, wl, jac);

    gemm_kernel<<<4 * 128, 512, 0, stream>>>(x, wh, wl, bias, y);
}